// Round 14
// baseline (515.225 us; speedup 1.0000x reference)
//
#include <hip/hip_runtime.h>
#include <hip/hip_bf16.h>

#define B_    16
#define C_    96
#define H_    224
#define W_    224
#define COUT_ 96
#define GH_   14
#define GW_   14
#define P_    196          // GH_*GW_
#define HW_   (H_*W_)      // 50176
#define NCH_  12           // 8-channel chunks

#define AS1 __attribute__((address_space(1)))
#define AS3 __attribute__((address_space(3)))

typedef __attribute__((ext_vector_type(8))) unsigned short ushort8;
typedef __attribute__((ext_vector_type(8))) short        short8;   // MFMA bf16x8 operand
typedef __attribute__((ext_vector_type(4))) float        f32x4;

__device__ __forceinline__ unsigned short f2bf(float f) {
    union { __hip_bfloat16 h; unsigned short u; } cv;
    cv.h = __float2bfloat16(f);
    return cv.u;
}

// ---------------------------------------------------------------------------
// Kernel 0: of (COUT,C,3,3) f32 -> ofb2[T][cout][36] bf16 (T = g*9+tap),
// rows PRE-PADDED to 36 ushorts so global_load_lds can stage a (g,tap) tile
// linearly into a bank-friendly LDS layout. Also zeroes the OOB zero-page.
// ---------------------------------------------------------------------------
__global__ __launch_bounds__(256) void prep_ofb(const float* __restrict__ of,
                                                unsigned short* __restrict__ ofb2,
                                                unsigned short* __restrict__ zp) {
    if (blockIdx.x == 0 && threadIdx.x < 128) zp[threadIdx.x] = 0;
    int e = blockIdx.x * 256 + threadIdx.x;        // 27*96*36 = 93312
    if (e < 27 * 96 * 36) {
        int T = e / 3456;
        int r = e % 3456;
        int cout = r / 36, q = r % 36;
        int g = T / 9, tap = T % 9;
        unsigned short v = 0;
        if (q < 32)
            v = f2bf(of[((size_t)cout * 96 + g * 32 + q) * 9 + tap]);
        ofb2[e] = v;
    }
}

// ---------------------------------------------------------------------------
// Kernel 1: per-patch depthwise 3x3 (patch-local zero padding).
// x: (B,C,H,W) f32 -> sa: (B, 12, H, W, 8) bf16  (8-ch chunk planes).
// (R5-proven: ~107 us, near traffic floor. Unchanged.)
// ---------------------------------------------------------------------------
__global__ __launch_bounds__(256) void sa_kernel(const float* __restrict__ x,
                                                 const float* __restrict__ pf,
                                                 unsigned short* __restrict__ sa) {
    int bid   = blockIdx.x;
    int patch = bid % P_;
    int b     = bid / P_;
    int gh = patch / GW_, gw = patch % GW_;
    int t  = threadIdx.x;
    int py = t >> 4, px = t & 15;
    int y  = gh * 16 + py, xx = gw * 16 + px;

    __shared__ float xs[2][8][256];    // 16 KB double-buffered x slice

    const float* xp0 = x + (size_t)b * C_ * HW_ + (size_t)y * W_ + xx;

    float lf[8];
    #pragma unroll
    for (int ch = 0; ch < 8; ++ch) lf[ch] = xp0[(size_t)ch * HW_];

    for (int cc = 0; cc < NCH_; ++cc) {
        int buf = cc & 1;
        #pragma unroll
        for (int ch = 0; ch < 8; ++ch) xs[buf][ch][t] = lf[ch];
        __syncthreads();
        if (cc < NCH_ - 1) {
            #pragma unroll
            for (int ch = 0; ch < 8; ++ch)
                lf[ch] = xp0[(size_t)((cc + 1) * 8 + ch) * HW_];
        }

        ushort8 v;
        #pragma unroll
        for (int ch = 0; ch < 8; ++ch) {
            const float* wgt = pf + ((size_t)(cc * 8 + ch) * P_ + patch) * 9;  // uniform -> s_load
            float a = 0.f;
            #pragma unroll
            for (int dy = -1; dy <= 1; ++dy) {
                int yy = py + dy;
                if ((unsigned)yy < 16u) {
                    #pragma unroll
                    for (int dx = -1; dx <= 1; ++dx) {
                        int xq = px + dx;
                        if ((unsigned)xq < 16u)
                            a = fmaf(xs[buf][ch][yy * 16 + xq],
                                     wgt[(dy + 1) * 3 + (dx + 1)], a);
                    }
                }
            }
            v[ch] = f2bf(a);
        }
        *(ushort8*)&sa[(((size_t)(b * NCH_ + cc) * H_ + y) * W_ + xx) * 8] = v;
    }
}

// ---------------------------------------------------------------------------
// Kernel 2: implicit-GEMM MFMA conv + exact GELU, full-patch blocks.
// R14 = m97-replica K-loop (the structure measured at 37% MfmaUtil on this
// chip) applied to conv2:
//   - A: 18x18x12-plane halo staged ONCE via global_load_lds (64 KB, R13);
//   - B: per-(g,tap) 96x36-row tile in a DOUBLE-BUFFERED LDS ring
//     (2 x 7168 B), staged via global_load_lds from pre-padded ofb2;
//     per step: stage B(T+1) -> ds_read af/bf of T -> 24 MFMA -> barrier.
//     Waves share the B copy (L2 B-traffic 2.0 GB -> 0.59 GB) and the only
//     vmcnt dependency in the loop is the next tile (hidden under MFMA).
//   - 4 all-M waves, acc[4][6]; row pitch 36 -> bank starts r*18 mod 32,
//     all-distinct -> ~2-way (free).
// ---------------------------------------------------------------------------
__global__ __launch_bounds__(256, 2) void conv2_mfma(const unsigned short* __restrict__ sa,
                                                     const unsigned short* __restrict__ ofb2,
                                                     const unsigned short* __restrict__ zp,
                                                     float* __restrict__ out) {
    // XCD-aware swizzle (3136 % 8 == 0 -> bijective)
    int bid0 = blockIdx.x;
    int bid  = (bid0 % 8) * (3136 / 8) + bid0 / 8;
    int patch = bid % P_;
    int b     = bid / P_;
    int gh = patch / GW_, gw = patch % GW_;
    int y0 = gh * 16, x0 = gw * 16;

    int t = threadIdx.x;
    int w = t >> 6, l = t & 63;             // 4 all-M waves
    int mrow = l & 15, kgrp = l >> 4;

    __shared__ ushort8 at8[4096];           // A: 3888 tile + 208 trash = 65536 B
    __shared__ unsigned short bt[2][3584];  // B ring: 448 chunks x 16 B = 7168 B/slot

    // ---- A: single staging burst (whole 18x18 halo, all 12 planes) ----
    #pragma unroll
    for (int i = 0; i < 16; ++i) {
        int v = t + i * 256;                // 0..4095; [0,3888) real
        const unsigned short* src = zp;
        if (v < 3888) {
            int ccl = v / 324, hpx = v - ccl * 324;
            int gy = y0 - 1 + hpx / 18, gx = x0 - 1 + hpx % 18;
            if ((unsigned)gy < (unsigned)H_ && (unsigned)gx < (unsigned)W_)
                src = &sa[(((size_t)(b * NCH_ + ccl) * H_ + gy) * W_ + gx) * 8];
        }
        __builtin_amdgcn_global_load_lds((const AS1 unsigned int*)src,
                                         (AS3 unsigned int*)&at8[v], 16, 0, 0);
    }

    // ---- B: stage tile T into ring slot T&1 (wave-uniform issue counts) ----
    auto STAGE_B = [&](int T) {
        unsigned short* dst = &bt[T & 1][0];
        #pragma unroll
        for (int i = 0; i < 2; ++i) {
            int v = t + i * 256;            // 0..511; issue v<448 (wave 3 skips i=1)
            if (v < 448) {
                const unsigned short* src = zp;
                if (v < 432) src = ofb2 + (size_t)T * 3456 + v * 8;
                __builtin_amdgcn_global_load_lds((const AS1 unsigned int*)src,
                                                 (AS3 unsigned int*)&dst[v * 8], 16, 0, 0);
            }
        }
    };

    f32x4 acc[4][6];
    #pragma unroll
    for (int mi = 0; mi < 4; ++mi)
        #pragma unroll
        for (int ni = 0; ni < 6; ++ni)
            acc[mi][ni] = (f32x4)0.f;

    STAGE_B(0);
    __syncthreads();                        // drain A + B(0); queue empty

    const unsigned short* at = (const unsigned short*)at8;

    #pragma unroll                          // full unroll: ring index static
    for (int T = 0; T < 27; ++T) {
        if (T + 1 < 27) STAGE_B(T + 1);     // in flight across this step's MFMAs

        int g = T / 9, tap = T % 9;
        int ky = tap / 3, kx = tap % 3;
        const unsigned short* bbuf = &bt[T & 1][0];

        short8 bf[6];
        #pragma unroll
        for (int ni = 0; ni < 6; ++ni)
            bf[ni] = *(const short8*)&bbuf[(ni * 16 + mrow) * 36 + kgrp * 8];
        #pragma unroll
        for (int mi = 0; mi < 4; ++mi) {
            short8 af = *(const short8*)&at[((g * 4 + kgrp) * 324
                                            + (w * 4 + mi + ky) * 18
                                            + kx + mrow) * 8];
            #pragma unroll
            for (int ni = 0; ni < 6; ++ni)
                acc[mi][ni] = __builtin_amdgcn_mfma_f32_16x16x32_bf16(
                    af, bf[ni], acc[mi][ni], 0, 0, 0);
        }

        if (T < 26) __syncthreads();        // drains stage of T+1, WAR-safe ring
    }

    // ---- epilogue: exact GELU + f32x4 stores ----
    #pragma unroll
    for (int mi = 0; mi < 4; ++mi) {
        int gy = y0 + w * 4 + mi;
        #pragma unroll
        for (int ni = 0; ni < 6; ++ni) {
            int cout = ni * 16 + mrow;
            f32x4 gv;
            #pragma unroll
            for (int j = 0; j < 4; ++j) {
                float vv = acc[mi][ni][j];
                gv[j] = 0.5f * vv * (1.0f + erff(vv * 0.70710678118f));
            }
            *(f32x4*)&out[((size_t)b * COUT_ + cout) * HW_ + (size_t)gy * W_ +
                          x0 + kgrp * 4] = gv;
        }
    }
}

extern "C" void kernel_launch(void* const* d_in, const int* in_sizes, int n_in,
                              void* d_out, int out_size, void* d_ws, size_t ws_size,
                              hipStream_t stream) {
    const float* x  = (const float*)d_in[0];
    const float* pf = (const float*)d_in[1];
    const float* of = (const float*)d_in[2];
    float* out = (float*)d_out;

    unsigned short* sa   = (unsigned short*)d_ws;                       // 154,140,672 B
    unsigned short* ofb2 = (unsigned short*)((char*)d_ws + 154140672);  // + 186,624 B
    unsigned short* zp   = (unsigned short*)((char*)d_ws + 154327296);  // + 256 B zero-page

    prep_ofb<<<365, 256, 0, stream>>>(of, ofb2, zp);
    sa_kernel<<<B_ * P_, 256, 0, stream>>>(x, pf, sa);
    conv2_mfma<<<B_ * P_, 256, 0, stream>>>(sa, ofb2, zp, out);
}

// Round 15
// 412.548 us; speedup vs baseline: 1.2489x; 1.2489x over previous
//
#include <hip/hip_runtime.h>
#include <hip/hip_bf16.h>

#define B_    16
#define C_    96
#define H_    224
#define W_    224
#define COUT_ 96
#define GH_   14
#define GW_   14
#define P_    196          // GH_*GW_
#define HW_   (H_*W_)      // 50176
#define NCH_  12           // 8-channel chunks

#define AS1 __attribute__((address_space(1)))
#define AS3 __attribute__((address_space(3)))

typedef __attribute__((ext_vector_type(8))) unsigned short ushort8;
typedef __attribute__((ext_vector_type(8))) short        short8;   // MFMA bf16x8 operand
typedef __attribute__((ext_vector_type(4))) float        f32x4;

__device__ __forceinline__ unsigned short f2bf(float f) {
    union { __hip_bfloat16 h; unsigned short u; } cv;
    cv.h = __float2bfloat16(f);
    return cv.u;
}

// ---------------------------------------------------------------------------
// Kernel 0: of (COUT,C,3,3) f32 -> ofb[tap][cout][c] bf16; zero-page for OOB.
// ---------------------------------------------------------------------------
__global__ __launch_bounds__(256) void prep_ofb(const float* __restrict__ of,
                                                unsigned short* __restrict__ ofb,
                                                unsigned short* __restrict__ zp) {
    if (blockIdx.x == 0 && threadIdx.x < 128) zp[threadIdx.x] = 0;
    int idx = blockIdx.x * 256 + threadIdx.x;      // 9*96*96 = 82944
    if (idx < 9 * 96 * 96) {
        int tap = idx / (96 * 96);
        int r   = idx % (96 * 96);
        int cout = r / 96, c = r % 96;
        ofb[idx] = f2bf(of[((size_t)cout * 96 + c) * 9 + tap]);
    }
}

// ---------------------------------------------------------------------------
// Kernel 1: per-patch depthwise 3x3 (patch-local zero padding).
// x: (B,C,H,W) f32 -> sa: (B, 12, H, W, 8) bf16  (8-ch chunk planes).
// (R5-proven: ~107 us, near traffic floor. Unchanged.)
// ---------------------------------------------------------------------------
__global__ __launch_bounds__(256) void sa_kernel(const float* __restrict__ x,
                                                 const float* __restrict__ pf,
                                                 unsigned short* __restrict__ sa) {
    int bid   = blockIdx.x;
    int patch = bid % P_;
    int b     = bid / P_;
    int gh = patch / GW_, gw = patch % GW_;
    int t  = threadIdx.x;
    int py = t >> 4, px = t & 15;
    int y  = gh * 16 + py, xx = gw * 16 + px;

    __shared__ float xs[2][8][256];    // 16 KB double-buffered x slice

    const float* xp0 = x + (size_t)b * C_ * HW_ + (size_t)y * W_ + xx;

    float lf[8];
    #pragma unroll
    for (int ch = 0; ch < 8; ++ch) lf[ch] = xp0[(size_t)ch * HW_];

    for (int cc = 0; cc < NCH_; ++cc) {
        int buf = cc & 1;
        #pragma unroll
        for (int ch = 0; ch < 8; ++ch) xs[buf][ch][t] = lf[ch];
        __syncthreads();
        if (cc < NCH_ - 1) {
            #pragma unroll
            for (int ch = 0; ch < 8; ++ch)
                lf[ch] = xp0[(size_t)((cc + 1) * 8 + ch) * HW_];
        }

        ushort8 v;
        #pragma unroll
        for (int ch = 0; ch < 8; ++ch) {
            const float* wgt = pf + ((size_t)(cc * 8 + ch) * P_ + patch) * 9;  // uniform -> s_load
            float a = 0.f;
            #pragma unroll
            for (int dy = -1; dy <= 1; ++dy) {
                int yy = py + dy;
                if ((unsigned)yy < 16u) {
                    #pragma unroll
                    for (int dx = -1; dx <= 1; ++dx) {
                        int xq = px + dx;
                        if ((unsigned)xq < 16u)
                            a = fmaf(xs[buf][ch][yy * 16 + xq],
                                     wgt[(dy + 1) * 3 + (dx + 1)], a);
                    }
                }
            }
            v[ch] = f2bf(a);
        }
        *(ushort8*)&sa[(((size_t)(b * NCH_ + cc) * H_ + y) * W_ + xx) * 8] = v;
    }
}

// ---------------------------------------------------------------------------
// Kernel 2: implicit-GEMM MFMA conv + exact GELU, full-patch blocks.
// R15 = the measured-best R2 K-loop, modernized prologue only:
//   - A tile PX-MAJOR [18x18 px][96 ch] (R2's layout), staged ONCE via
//     global_load_lds (task v -> linear LDS = px-major automatically since
//     v = hpx*12 + ccl), one barrier, vmcnt queue empty in the loop;
//   - K-loop: tap outer (#pragma unroll 1 -> 72-MFMA window), cs(3) inner
//     unrolled; per cs: 6 bf global loads -> 4 af ds_reads -> 24 MFMA;
//     ZERO in-loop barriers (R14's per-tap DMA+barrier was the regression:
//     every barrier drains vmcnt(0) -> serial L2 round-trip per step);
//   - acc[4][6], 4 all-M waves, launch_bounds(256,2) (~160 arch regs).
// R13 isolates the two variables reverted here: full 648-unroll + plane-
// major layout cost +60 us vs this shape (303 vs 243).
// ---------------------------------------------------------------------------
__global__ __launch_bounds__(256, 2) void conv2_mfma(const unsigned short* __restrict__ sa,
                                                     const unsigned short* __restrict__ ofb,
                                                     const unsigned short* __restrict__ zp,
                                                     float* __restrict__ out) {
    // XCD-aware swizzle (3136 % 8 == 0 -> bijective)
    int bid0 = blockIdx.x;
    int bid  = (bid0 % 8) * (3136 / 8) + bid0 / 8;
    int patch = bid % P_;
    int b     = bid / P_;
    int gh = patch / GW_, gw = patch % GW_;
    int y0 = gh * 16, x0 = gw * 16;

    int t = threadIdx.x;
    int w = t >> 6, l = t & 63;             // 4 all-M waves
    int mrow = l & 15, kgrp = l >> 4;

    __shared__ ushort8 at8[4096];           // 3888 tile + 208 trash = 65536 B

    // ---- single staging burst: 18x18 halo, px-major [hpx][12 chunks] ----
    #pragma unroll
    for (int i = 0; i < 16; ++i) {
        int v = t + i * 256;                // 0..4095; [0,3888) real
        const unsigned short* src = zp;
        if (v < 3888) {
            int hpx = v / 12, ccl = v - hpx * 12;   // px-major task order
            int gy = y0 - 1 + hpx / 18, gx = x0 - 1 + hpx % 18;
            if ((unsigned)gy < (unsigned)H_ && (unsigned)gx < (unsigned)W_)
                src = &sa[(((size_t)(b * NCH_ + ccl) * H_ + gy) * W_ + gx) * 8];
        }
        __builtin_amdgcn_global_load_lds((const AS1 unsigned int*)src,
                                         (AS3 unsigned int*)&at8[v], 16, 0, 0);
    }

    f32x4 acc[4][6];
    #pragma unroll
    for (int mi = 0; mi < 4; ++mi)
        #pragma unroll
        for (int ni = 0; ni < 6; ++ni)
            acc[mi][ni] = (f32x4)0.f;

    __syncthreads();                        // drain DMA; tile visible; queue EMPTY

    const unsigned short* at = (const unsigned short*)at8;  // [px][96 ch]

    // ---- R2's K-loop: 9 taps x (3 cs x {6 bf, 4 af, 24 MFMA}) ----
    #pragma unroll 1
    for (int tap = 0; tap < 9; ++tap) {
        int ky = tap / 3, kx = tap % 3;
        const unsigned short* bofs0 = ofb + tap * (96 * 96) + kgrp * 8;
        #pragma unroll
        for (int cs = 0; cs < 3; ++cs) {
            short8 bf[6];
            #pragma unroll
            for (int ni = 0; ni < 6; ++ni)
                bf[ni] = *(const short8*)&bofs0[(ni * 16 + mrow) * 96 + cs * 32];
            #pragma unroll
            for (int mi = 0; mi < 4; ++mi) {
                short8 af = *(const short8*)&at[((w * 4 + mi + ky) * 18 + kx + mrow) * 96
                                                + cs * 32 + kgrp * 8];
                #pragma unroll
                for (int ni = 0; ni < 6; ++ni)
                    acc[mi][ni] = __builtin_amdgcn_mfma_f32_16x16x32_bf16(
                        af, bf[ni], acc[mi][ni], 0, 0, 0);
            }
        }
    }

    // ---- epilogue: exact GELU + f32x4 stores ----
    #pragma unroll
    for (int mi = 0; mi < 4; ++mi) {
        int gy = y0 + w * 4 + mi;
        #pragma unroll
        for (int ni = 0; ni < 6; ++ni) {
            int cout = ni * 16 + mrow;
            f32x4 gv;
            #pragma unroll
            for (int j = 0; j < 4; ++j) {
                float vv = acc[mi][ni][j];
                gv[j] = 0.5f * vv * (1.0f + erff(vv * 0.70710678118f));
            }
            *(f32x4*)&out[((size_t)b * COUT_ + cout) * HW_ + (size_t)gy * W_ +
                          x0 + kgrp * 4] = gv;
        }
    }
}

extern "C" void kernel_launch(void* const* d_in, const int* in_sizes, int n_in,
                              void* d_out, int out_size, void* d_ws, size_t ws_size,
                              hipStream_t stream) {
    const float* x  = (const float*)d_in[0];
    const float* pf = (const float*)d_in[1];
    const float* of = (const float*)d_in[2];
    float* out = (float*)d_out;

    unsigned short* sa  = (unsigned short*)d_ws;                       // 154,140,672 B
    unsigned short* ofb = (unsigned short*)((char*)d_ws + 154140672);  // + 165,888 B
    unsigned short* zp  = (unsigned short*)((char*)d_ws + 154306560);  // + 256 B zero-page

    prep_ofb<<<324, 256, 0, stream>>>(of, ofb, zp);
    sa_kernel<<<B_ * P_, 256, 0, stream>>>(x, pf, sa);
    conv2_mfma<<<B_ * P_, 256, 0, stream>>>(sa, ofb, zp, out);
}

// Round 16
// 386.524 us; speedup vs baseline: 1.3330x; 1.0673x over previous
//
#include <hip/hip_runtime.h>
#include <hip/hip_bf16.h>

#define B_    16
#define C_    96
#define H_    224
#define W_    224
#define COUT_ 96
#define GH_   14
#define GW_   14
#define P_    196          // GH_*GW_
#define HW_   (H_*W_)      // 50176
#define NCH_  12           // 8-channel chunks

#define AS1 __attribute__((address_space(1)))
#define AS3 __attribute__((address_space(3)))

typedef __attribute__((ext_vector_type(8))) unsigned short ushort8;
typedef __attribute__((ext_vector_type(8))) short        short8;   // MFMA bf16x8 operand
typedef __attribute__((ext_vector_type(4))) float        f32x4;

__device__ __forceinline__ unsigned short f2bf(float f) {
    union { __hip_bfloat16 h; unsigned short u; } cv;
    cv.h = __float2bfloat16(f);
    return cv.u;
}

// ---------------------------------------------------------------------------
// Kernel 0: of (COUT,C,3,3) f32 -> ofb3 in MFMA-FRAGMENT ORDER:
//   ofb3[tap][cs][ni][lane][8ch],  lane = mrow + 16*kgrp,
//   cout = ni*16 + (lane&15), c = cs*32 + (lane>>4)*8 + j.
// A wave's bf load for (tap,cs,ni) is then base + lane*16B: fully coalesced
// 1 KB, identical across waves (L1-friendly). Also zeroes the OOB zero-page.
// ---------------------------------------------------------------------------
__global__ __launch_bounds__(256) void prep_ofb(const float* __restrict__ of,
                                                unsigned short* __restrict__ ofb3,
                                                unsigned short* __restrict__ zp) {
    if (blockIdx.x == 0 && threadIdx.x < 128) zp[threadIdx.x] = 0;
    int e = blockIdx.x * 256 + threadIdx.x;        // 9*3*6*64*8 = 82944
    if (e < 82944) {
        int j    = e & 7;
        int l    = (e >> 3) & 63;
        int ni   = (e >> 9) % 6;
        int cs   = (e / 3072) % 3;
        int tap  = e / 9216;
        int cout = ni * 16 + (l & 15);
        int c    = cs * 32 + (l >> 4) * 8 + j;
        ofb3[e] = f2bf(of[((size_t)cout * 96 + c) * 9 + tap]);
    }
}

// ---------------------------------------------------------------------------
// Kernel 1: per-patch depthwise 3x3 (patch-local zero padding).
// x: (B,C,H,W) f32 -> sa: (B, 12, H, W, 8) bf16  (8-ch chunk planes).
// (R5-proven: ~107 us, near traffic floor. Unchanged.)
// ---------------------------------------------------------------------------
__global__ __launch_bounds__(256) void sa_kernel(const float* __restrict__ x,
                                                 const float* __restrict__ pf,
                                                 unsigned short* __restrict__ sa) {
    int bid   = blockIdx.x;
    int patch = bid % P_;
    int b     = bid / P_;
    int gh = patch / GW_, gw = patch % GW_;
    int t  = threadIdx.x;
    int py = t >> 4, px = t & 15;
    int y  = gh * 16 + py, xx = gw * 16 + px;

    __shared__ float xs[2][8][256];    // 16 KB double-buffered x slice

    const float* xp0 = x + (size_t)b * C_ * HW_ + (size_t)y * W_ + xx;

    float lf[8];
    #pragma unroll
    for (int ch = 0; ch < 8; ++ch) lf[ch] = xp0[(size_t)ch * HW_];

    for (int cc = 0; cc < NCH_; ++cc) {
        int buf = cc & 1;
        #pragma unroll
        for (int ch = 0; ch < 8; ++ch) xs[buf][ch][t] = lf[ch];
        __syncthreads();
        if (cc < NCH_ - 1) {
            #pragma unroll
            for (int ch = 0; ch < 8; ++ch)
                lf[ch] = xp0[(size_t)((cc + 1) * 8 + ch) * HW_];
        }

        ushort8 v;
        #pragma unroll
        for (int ch = 0; ch < 8; ++ch) {
            const float* wgt = pf + ((size_t)(cc * 8 + ch) * P_ + patch) * 9;  // uniform -> s_load
            float a = 0.f;
            #pragma unroll
            for (int dy = -1; dy <= 1; ++dy) {
                int yy = py + dy;
                if ((unsigned)yy < 16u) {
                    #pragma unroll
                    for (int dx = -1; dx <= 1; ++dx) {
                        int xq = px + dx;
                        if ((unsigned)xq < 16u)
                            a = fmaf(xs[buf][ch][yy * 16 + xq],
                                     wgt[(dy + 1) * 3 + (dx + 1)], a);
                    }
                }
            }
            v[ch] = f2bf(a);
        }
        *(ushort8*)&sa[(((size_t)(b * NCH_ + cc) * H_ + y) * W_ + xx) * 8] = v;
    }
}

// ---------------------------------------------------------------------------
// Kernel 2: implicit-GEMM MFMA conv + exact GELU, full-patch blocks.
// R16 = R15 structure with the two measured pathologies fixed:
//   (a) bf loads now read ofb3 fragment-order: base + lane*16B, coalesced
//       (R15: lane stride 192B -> 16 cachelines/load, L1-thrashing 166 KB
//       stream = the occupancy-insensitive ~280 us floor suspect);
//   (b) A tile pitch = 13 slots/px (208 B): mrow residues mod 128 spread
//       8-wide -> ~2-way banks (R15's 192 B pitch: 2 residues -> 8-way,
//       5.4M conflict cycles). Pad slot 12 is written from zp, never read.
// Everything else identical: stage-once DMA prologue, one barrier, tap-outer
// #pragma unroll 1 (72-MFMA window), acc[4][6], 4 all-M waves, (256,2).
// ---------------------------------------------------------------------------
__global__ __launch_bounds__(256, 2) void conv2_mfma(const unsigned short* __restrict__ sa,
                                                     const unsigned short* __restrict__ ofb3,
                                                     const unsigned short* __restrict__ zp,
                                                     float* __restrict__ out) {
    // XCD-aware swizzle (3136 % 8 == 0 -> bijective)
    int bid0 = blockIdx.x;
    int bid  = (bid0 % 8) * (3136 / 8) + bid0 / 8;
    int patch = bid % P_;
    int b     = bid / P_;
    int gh = patch / GW_, gw = patch % GW_;
    int y0 = gh * 16, x0 = gw * 16;

    int t = threadIdx.x;
    int w = t >> 6, l = t & 63;             // 4 all-M waves
    int mrow = l & 15, kgrp = l >> 4;

    __shared__ ushort8 at8[4352];           // 18*18 px x 13 slots = 4212 (+140 trash) = 69632 B

    // ---- single staging burst: 18x18 halo, px-major, 13-slot pitch ----
    #pragma unroll
    for (int i = 0; i < 17; ++i) {
        int v = t + i * 256;                // 0..4351; [0,4212) real
        const unsigned short* src = zp;
        if (v < 4212) {
            int hpx = v / 13, ccl = v - hpx * 13;   // ccl 12 = bank-pad slot (from zp)
            if (ccl < 12) {
                int gy = y0 - 1 + hpx / 18, gx = x0 - 1 + hpx % 18;
                if ((unsigned)gy < (unsigned)H_ && (unsigned)gx < (unsigned)W_)
                    src = &sa[(((size_t)(b * NCH_ + ccl) * H_ + gy) * W_ + gx) * 8];
            }
        }
        __builtin_amdgcn_global_load_lds((const AS1 unsigned int*)src,
                                         (AS3 unsigned int*)&at8[v], 16, 0, 0);
    }

    f32x4 acc[4][6];
    #pragma unroll
    for (int mi = 0; mi < 4; ++mi)
        #pragma unroll
        for (int ni = 0; ni < 6; ++ni)
            acc[mi][ni] = (f32x4)0.f;

    __syncthreads();                        // drain DMA; tile visible; queue EMPTY

    const unsigned short* at = (const unsigned short*)at8;  // [px][13 slots][8ch]

    // ---- K-loop: 9 taps x (3 cs x {6 coalesced bf, 4 af, 24 MFMA}) ----
    #pragma unroll 1
    for (int tap = 0; tap < 9; ++tap) {
        int ky = tap / 3, kx = tap % 3;
        const unsigned short* bofs0 = ofb3 + (size_t)tap * 9216 + l * 8;  // + lane*16B
        #pragma unroll
        for (int cs = 0; cs < 3; ++cs) {
            short8 bf[6];
            #pragma unroll
            for (int ni = 0; ni < 6; ++ni)
                bf[ni] = *(const short8*)&bofs0[(cs * 6 + ni) * 512];
            #pragma unroll
            for (int mi = 0; mi < 4; ++mi) {
                short8 af = *(const short8*)&at[((w * 4 + mi + ky) * 18 + kx + mrow) * 104
                                                + (cs * 4 + kgrp) * 8];
                #pragma unroll
                for (int ni = 0; ni < 6; ++ni)
                    acc[mi][ni] = __builtin_amdgcn_mfma_f32_16x16x32_bf16(
                        af, bf[ni], acc[mi][ni], 0, 0, 0);
            }
        }
    }

    // ---- epilogue: exact GELU + f32x4 stores ----
    #pragma unroll
    for (int mi = 0; mi < 4; ++mi) {
        int gy = y0 + w * 4 + mi;
        #pragma unroll
        for (int ni = 0; ni < 6; ++ni) {
            int cout = ni * 16 + mrow;
            f32x4 gv;
            #pragma unroll
            for (int j = 0; j < 4; ++j) {
                float vv = acc[mi][ni][j];
                gv[j] = 0.5f * vv * (1.0f + erff(vv * 0.70710678118f));
            }
            *(f32x4*)&out[((size_t)b * COUT_ + cout) * HW_ + (size_t)gy * W_ +
                          x0 + kgrp * 4] = gv;
        }
    }
}

extern "C" void kernel_launch(void* const* d_in, const int* in_sizes, int n_in,
                              void* d_out, int out_size, void* d_ws, size_t ws_size,
                              hipStream_t stream) {
    const float* x  = (const float*)d_in[0];
    const float* pf = (const float*)d_in[1];
    const float* of = (const float*)d_in[2];
    float* out = (float*)d_out;

    unsigned short* sa   = (unsigned short*)d_ws;                       // 154,140,672 B
    unsigned short* ofb3 = (unsigned short*)((char*)d_ws + 154140672);  // + 165,888 B
    unsigned short* zp   = (unsigned short*)((char*)d_ws + 154306560);  // + 256 B zero-page

    prep_ofb<<<324, 256, 0, stream>>>(of, ofb3, zp);
    sa_kernel<<<B_ * P_, 256, 0, stream>>>(x, pf, sa);
    conv2_mfma<<<B_ * P_, 256, 0, stream>>>(sa, ofb3, zp, out);
}

// Round 17
// 355.829 us; speedup vs baseline: 1.4480x; 1.0863x over previous
//
#include <hip/hip_runtime.h>
#include <hip/hip_bf16.h>

#define B_    16
#define C_    96
#define H_    224
#define W_    224
#define COUT_ 96
#define GH_   14
#define GW_   14
#define P_    196          // GH_*GW_
#define HW_   (H_*W_)      // 50176
#define NCH_  12           // 8-channel chunks

#define AS1 __attribute__((address_space(1)))
#define AS3 __attribute__((address_space(3)))

typedef __attribute__((ext_vector_type(8))) unsigned short ushort8;
typedef __attribute__((ext_vector_type(8))) short        short8;   // MFMA bf16x8 operand
typedef __attribute__((ext_vector_type(4))) float        f32x4;

__device__ __forceinline__ unsigned short f2bf(float f) {
    union { __hip_bfloat16 h; unsigned short u; } cv;
    cv.h = __float2bfloat16(f);
    return cv.u;
}

// ---------------------------------------------------------------------------
// Kernel 0: of (COUT,C,3,3) f32 -> ofb3 in MFMA-FRAGMENT ORDER:
//   ofb3[tap][cs][ni][lane][8ch],  lane = mrow + 16*kgrp,
//   cout = ni*16 + (lane&15), c = cs*32 + (lane>>4)*8 + j.
// Wave bf load = base + lane*16B: coalesced 1 KB, same across waves.
// ---------------------------------------------------------------------------
__global__ __launch_bounds__(256) void prep_ofb(const float* __restrict__ of,
                                                unsigned short* __restrict__ ofb3,
                                                unsigned short* __restrict__ zp) {
    if (blockIdx.x == 0 && threadIdx.x < 128) zp[threadIdx.x] = 0;
    int e = blockIdx.x * 256 + threadIdx.x;        // 9*3*6*64*8 = 82944
    if (e < 82944) {
        int j    = e & 7;
        int l    = (e >> 3) & 63;
        int ni   = (e >> 9) % 6;
        int cs   = (e / 3072) % 3;
        int tap  = e / 9216;
        int cout = ni * 16 + (l & 15);
        int c    = cs * 32 + (l >> 4) * 8 + j;
        ofb3[e] = f2bf(of[((size_t)cout * 96 + c) * 9 + tap]);
    }
}

// ---------------------------------------------------------------------------
// Kernel 1: per-patch depthwise 3x3 (patch-local zero padding).
// x: (B,C,H,W) f32 -> sa: (B, 12, H, W, 8) bf16  (8-ch chunk planes).
// (R5-proven: ~107 us, near traffic floor. Unchanged.)
// ---------------------------------------------------------------------------
__global__ __launch_bounds__(256) void sa_kernel(const float* __restrict__ x,
                                                 const float* __restrict__ pf,
                                                 unsigned short* __restrict__ sa) {
    int bid   = blockIdx.x;
    int patch = bid % P_;
    int b     = bid / P_;
    int gh = patch / GW_, gw = patch % GW_;
    int t  = threadIdx.x;
    int py = t >> 4, px = t & 15;
    int y  = gh * 16 + py, xx = gw * 16 + px;

    __shared__ float xs[2][8][256];    // 16 KB double-buffered x slice

    const float* xp0 = x + (size_t)b * C_ * HW_ + (size_t)y * W_ + xx;

    float lf[8];
    #pragma unroll
    for (int ch = 0; ch < 8; ++ch) lf[ch] = xp0[(size_t)ch * HW_];

    for (int cc = 0; cc < NCH_; ++cc) {
        int buf = cc & 1;
        #pragma unroll
        for (int ch = 0; ch < 8; ++ch) xs[buf][ch][t] = lf[ch];
        __syncthreads();
        if (cc < NCH_ - 1) {
            #pragma unroll
            for (int ch = 0; ch < 8; ++ch)
                lf[ch] = xp0[(size_t)((cc + 1) * 8 + ch) * HW_];
        }

        ushort8 v;
        #pragma unroll
        for (int ch = 0; ch < 8; ++ch) {
            const float* wgt = pf + ((size_t)(cc * 8 + ch) * P_ + patch) * 9;  // uniform -> s_load
            float a = 0.f;
            #pragma unroll
            for (int dy = -1; dy <= 1; ++dy) {
                int yy = py + dy;
                if ((unsigned)yy < 16u) {
                    #pragma unroll
                    for (int dx = -1; dx <= 1; ++dx) {
                        int xq = px + dx;
                        if ((unsigned)xq < 16u)
                            a = fmaf(xs[buf][ch][yy * 16 + xq],
                                     wgt[(dy + 1) * 3 + (dx + 1)], a);
                    }
                }
            }
            v[ch] = f2bf(a);
        }
        *(ushort8*)&sa[(((size_t)(b * NCH_ + cc) * H_ + y) * W_ + xx) * 8] = v;
    }
}

// ---------------------------------------------------------------------------
// Kernel 2: implicit-GEMM MFMA conv + exact GELU, full-patch blocks.
// R17 = R16 + FORCED 1-step-ahead bf pipeline:
//   - 27 (tap,cs) steps FULLY unrolled; bf double-buffer bfA/bfB with
//     compile-time naming (rule #20);
//   - per step: issue 6 bf loads of step T+1 -> sched_barrier(0) fence
//     (pins issue order; R13's attempt died because the compiler sank the
//     loads back to their uses) -> 4x{af ds_read, 6 MFMA} of step T.
//     The wait before step T+1's MFMAs becomes a counted vmcnt(6) (T4),
//     hiding the B-stream L1/L2 latency under the 24-MFMA burst.
//   - Everything else identical to R16: fragment-order ofb3 (coalesced bf),
//     13-slot A-tile pitch, stage-once DMA prologue, one barrier,
//     acc[4][6], 4 all-M waves, launch_bounds(256,2).
// ---------------------------------------------------------------------------
__global__ __launch_bounds__(256, 2) void conv2_mfma(const unsigned short* __restrict__ sa,
                                                     const unsigned short* __restrict__ ofb3,
                                                     const unsigned short* __restrict__ zp,
                                                     float* __restrict__ out) {
    // XCD-aware swizzle (3136 % 8 == 0 -> bijective)
    int bid0 = blockIdx.x;
    int bid  = (bid0 % 8) * (3136 / 8) + bid0 / 8;
    int patch = bid % P_;
    int b     = bid / P_;
    int gh = patch / GW_, gw = patch % GW_;
    int y0 = gh * 16, x0 = gw * 16;

    int t = threadIdx.x;
    int w = t >> 6, l = t & 63;             // 4 all-M waves
    int mrow = l & 15, kgrp = l >> 4;

    __shared__ ushort8 at8[4352];           // 18*18 px x 13 slots (+140 trash) = 69632 B

    // ---- single staging burst: 18x18 halo, px-major, 13-slot pitch ----
    #pragma unroll
    for (int i = 0; i < 17; ++i) {
        int v = t + i * 256;                // 0..4351; [0,4212) real
        const unsigned short* src = zp;
        if (v < 4212) {
            int hpx = v / 13, ccl = v - hpx * 13;   // slot 12 = bank pad (zp)
            if (ccl < 12) {
                int gy = y0 - 1 + hpx / 18, gx = x0 - 1 + hpx % 18;
                if ((unsigned)gy < (unsigned)H_ && (unsigned)gx < (unsigned)W_)
                    src = &sa[(((size_t)(b * NCH_ + ccl) * H_ + gy) * W_ + gx) * 8];
            }
        }
        __builtin_amdgcn_global_load_lds((const AS1 unsigned int*)src,
                                         (AS3 unsigned int*)&at8[v], 16, 0, 0);
    }

    f32x4 acc[4][6];
    #pragma unroll
    for (int mi = 0; mi < 4; ++mi)
        #pragma unroll
        for (int ni = 0; ni < 6; ++ni)
            acc[mi][ni] = (f32x4)0.f;

    __syncthreads();                        // drain DMA; tile visible; queue EMPTY

    const unsigned short* at = (const unsigned short*)at8;  // [px][13 slots][8ch]

    // bf fetch for step T (tap = T/3, cs = T%3), fragment-order: +lane*16B
    short8 bfA[6], bfB[6];
    auto LOADBF = [&](short8* dst, int T) {
        const unsigned short* p = ofb3 + (size_t)(T / 3) * 9216 + (T % 3) * 3072 + l * 8;
        #pragma unroll
        for (int ni = 0; ni < 6; ++ni)
            dst[ni] = *(const short8*)&p[ni * 512];
    };

    LOADBF(bfA, 0);
    #pragma unroll                          // full unroll: bfA/bfB static
    for (int T = 0; T < 27; ++T) {
        short8* cur = (T & 1) ? bfB : bfA;
        short8* nxt = (T & 1) ? bfA : bfB;
        if (T + 1 < 27) LOADBF(nxt, T + 1); // issue-early (T14)
        __builtin_amdgcn_sched_barrier(0);  // pin loads above the MFMA burst

        int tap = T / 3, cs = T % 3;
        int ky = tap / 3, kx = tap % 3;
        #pragma unroll
        for (int mi = 0; mi < 4; ++mi) {
            short8 af = *(const short8*)&at[((w * 4 + mi + ky) * 18 + kx + mrow) * 104
                                            + (cs * 4 + kgrp) * 8];
            #pragma unroll
            for (int ni = 0; ni < 6; ++ni)
                acc[mi][ni] = __builtin_amdgcn_mfma_f32_16x16x32_bf16(
                    af, cur[ni], acc[mi][ni], 0, 0, 0);
        }
    }

    // ---- epilogue: exact GELU + f32x4 stores ----
    #pragma unroll
    for (int mi = 0; mi < 4; ++mi) {
        int gy = y0 + w * 4 + mi;
        #pragma unroll
        for (int ni = 0; ni < 6; ++ni) {
            int cout = ni * 16 + mrow;
            f32x4 gv;
            #pragma unroll
            for (int j = 0; j < 4; ++j) {
                float vv = acc[mi][ni][j];
                gv[j] = 0.5f * vv * (1.0f + erff(vv * 0.70710678118f));
            }
            *(f32x4*)&out[((size_t)b * COUT_ + cout) * HW_ + (size_t)gy * W_ +
                          x0 + kgrp * 4] = gv;
        }
    }
}

extern "C" void kernel_launch(void* const* d_in, const int* in_sizes, int n_in,
                              void* d_out, int out_size, void* d_ws, size_t ws_size,
                              hipStream_t stream) {
    const float* x  = (const float*)d_in[0];
    const float* pf = (const float*)d_in[1];
    const float* of = (const float*)d_in[2];
    float* out = (float*)d_out;

    unsigned short* sa   = (unsigned short*)d_ws;                       // 154,140,672 B
    unsigned short* ofb3 = (unsigned short*)((char*)d_ws + 154140672);  // + 165,888 B
    unsigned short* zp   = (unsigned short*)((char*)d_ws + 154306560);  // + 256 B zero-page

    prep_ofb<<<324, 256, 0, stream>>>(of, ofb3, zp);
    sa_kernel<<<B_ * P_, 256, 0, stream>>>(x, pf, sa);
    conv2_mfma<<<B_ * P_, 256, 0, stream>>>(sa, ofb3, zp, out);
}